// Round 6
// baseline (124.726 us; speedup 1.0000x reference)
//
#include <hip/hip_runtime.h>

// B=8, S=4096, E=256, H=4, DK=64. Tokens = B*S = 32768.
// Round-8: TLP via 2 independent blocks/CU. Rounds 5-7 (per-wave work cuts,
// LDS fixes, phase fusion) were ALL neutral at 1 block/CU -> binding constraint
// is zero cross-phase overlap: every barrier parks the whole CU.
//  - M=32 tokens/block, 512 thr (8 waves, wave = 32 rows x 32 cols, acc[2][2]).
//  - LDS 66KB (4 x 32-row buffers) -> 2 blocks/CU; __launch_bounds__(512,4)
//    -> 128 VGPR cap, 4 waves/SIMD. 1024 blocks = 2 full rounds, no tail.
//  - QKV merged pass (12 MFMA + 2 ds_read + 6 W-loads per kk); no explicit
//    W prefetch (TLP hides it; keeps regs under 128).
//  - softmax 16 thr/token (2-level shfl_xor), P redistributed by shfl, ymix
//    fused (no PL, no extra barrier). Y overwrites dead xs. 3 barriers total.

typedef __bf16 bf16x8 __attribute__((ext_vector_type(8)));
typedef __bf16 bf16x4 __attribute__((ext_vector_type(4)));
typedef float f32x4 __attribute__((ext_vector_type(4)));

#define LDW 264   // LDS row stride in bf16 elems (256+8 pad; rows stay 16B-aligned)
#define MROWS 32  // tokens per block
// row-dependent column swizzle (element units, 16-elem = 32B granularity)
#define XSW(row, col) ((col) ^ ((((row) >> 3) & 1) << 4))

// ---------- prep: pack W into fragment-contiguous bf16 (layout unchanged) ----------
// Fragment (p, g16, kk): lane(lh=lane&15, lq=lane>>4) holds
//   W_p[g16*16 + lh][kk*32 + lq*8 + j], j=0..7  (8 bf16 = 16B)
// stored at Wpk[frag_id*512 + lane*8], frag_id = p*128 + g16*8 + kk, g16 = 0..15.
__global__ void pack_wfrag(const float* __restrict__ Wq, const float* __restrict__ Wk,
                           const float* __restrict__ Wv, const float* __restrict__ Wo,
                           __bf16* __restrict__ Wpk) {
  const int f    = blockIdx.x;          // 0..511
  const int lane = threadIdx.x;         // 0..63
  const int kk  = f & 7;
  const int g16 = (f >> 3) & 15;
  const int p   = f >> 7;
  const float* W = (p == 0) ? Wq : (p == 1) ? Wk : (p == 2) ? Wv : Wo;
  const int lh = lane & 15, lq = lane >> 4;
  const int n  = g16 * 16 + lh;
  const int k0 = kk * 32 + lq * 8;
  const float4 s0 = *(const float4*)&W[n * 256 + k0];
  const float4 s1 = *(const float4*)&W[n * 256 + k0 + 4];
  bf16x8 r;
  r[0] = (__bf16)s0.x; r[1] = (__bf16)s0.y; r[2] = (__bf16)s0.z; r[3] = (__bf16)s0.w;
  r[4] = (__bf16)s1.x; r[5] = (__bf16)s1.y; r[6] = (__bf16)s1.z; r[7] = (__bf16)s1.w;
  *(bf16x8*)&Wpk[(size_t)f * 512 + lane * 8] = r;
}

#define MFMA(d, a, b) d = __builtin_amdgcn_mfma_f32_16x16x32_bf16(a, b, d, 0, 0, 0)

#define ZERO_ACC22(acc)                                          \
  _Pragma("unroll")                                              \
  for (int mf_ = 0; mf_ < 2; ++mf_)                              \
    _Pragma("unroll")                                            \
    for (int nf_ = 0; nf_ < 2; ++nf_)                            \
      acc[mf_][nf_] = (f32x4){0.f, 0.f, 0.f, 0.f};

// ---------- projection (32 rows x 32 cols): swizzled LDS A x streamed W ----------
__device__ __forceinline__ void proj32(const __bf16* __restrict__ as_,
                                       const __bf16* __restrict__ wl,  // + lane*8 applied
                                       int lh, int lq, f32x4 acc[2][2]) {
  const int xsw = ((lh >> 3) & 1) << 4;
  const __bf16* ap = as_ + lh * LDW;
  #pragma unroll
  for (int kk = 0; kk < 8; ++kk) {
    bf16x8 w0 = *(const bf16x8*)(wl + (0 * 8 + kk) * 512);
    bf16x8 w1 = *(const bf16x8*)(wl + (1 * 8 + kk) * 512);
    const int c = (kk * 32 + lq * 8) ^ xsw;
    bf16x8 a0 = *(const bf16x8*)(ap +  0 * LDW + c);
    bf16x8 a1 = *(const bf16x8*)(ap + 16 * LDW + c);
    MFMA(acc[0][0], a0, w0); MFMA(acc[1][0], a1, w0);
    MFMA(acc[0][1], a0, w1); MFMA(acc[1][1], a1, w1);
  }
}

__device__ __forceinline__ void store_cd32(__bf16* __restrict__ buf, const f32x4 acc[2][2],
                                           const float* __restrict__ bias,
                                           int n0, int lh, int lq) {
  #pragma unroll
  for (int nf = 0; nf < 2; ++nf) {
    int col = n0 + nf * 16 + lh;
    float bb = bias[col];
    #pragma unroll
    for (int mf = 0; mf < 2; ++mf) {
      int r = mf * 16 + lq * 4;
      #pragma unroll
      for (int j = 0; j < 4; ++j)
        buf[(r + j) * LDW + XSW(r + j, col)] = (__bf16)(acc[mf][nf][j] + bb);
    }
  }
}

__launch_bounds__(512, 4)
__global__ void fused_attn(const float* __restrict__ x, const __bf16* __restrict__ Wpk,
                           const float* __restrict__ bq, const float* __restrict__ bk,
                           const float* __restrict__ bv, const float* __restrict__ bo,
                           float* __restrict__ out) {
  __shared__ __bf16 xs[MROWS * LDW];    // x tile, then Y
  __shared__ __bf16 qs[MROWS * LDW];    // Q
  __shared__ __bf16 ksh[MROWS * LDW];   // K
  __shared__ __bf16 vs[MROWS * LDW];    // V

  const int tid  = threadIdx.x;          // 0..511
  const int lane = tid & 63;
  const int w    = tid >> 6;             // wave 0..7
  const int lh   = lane & 15;
  const int lq   = lane >> 4;
  const int n0   = w * 32;
  const int tok0 = blockIdx.x * MROWS;

  // ---- stage x tile: lane-contiguous float4 loads -> bf16 swizzled LDS ----
  const float4* xg = (const float4*)(x + (size_t)tok0 * 256);
  #pragma unroll
  for (int i = 0; i < 4; ++i) {
    int idx = i * 512 + tid;           // float4 id, 0..2047
    int row = idx >> 6;                // 64 float4 per row (rows 0..31)
    int c4  = idx & 63;
    float4 v = xg[idx];
    bf16x4 pk;
    pk[0] = (__bf16)v.x; pk[1] = (__bf16)v.y; pk[2] = (__bf16)v.z; pk[3] = (__bf16)v.w;
    *(bf16x4*)&xs[row * LDW + XSW(row, c4 * 4)] = pk;
  }

  // per-(proj,wave) packed-weight lane base: frag_id = p*128 + (2w+nf)*8 + kk
  const __bf16* wlq = Wpk + (size_t)(0 * 128 + w * 16) * 512 + lane * 8;
  const __bf16* wlk = Wpk + (size_t)(1 * 128 + w * 16) * 512 + lane * 8;
  const __bf16* wlv = Wpk + (size_t)(2 * 128 + w * 16) * 512 + lane * 8;
  const __bf16* wlo = Wpk + (size_t)(3 * 128 + w * 16) * 512 + lane * 8;

  __syncthreads();                       // x staged

  // ---- merged Q+K+V projection: one A-read pass, W streamed per-kk ----
  {
    f32x4 aq[2][2], ak[2][2], av[2][2];
    ZERO_ACC22(aq);
    ZERO_ACC22(ak);
    ZERO_ACC22(av);
    const int xsw = ((lh >> 3) & 1) << 4;
    const __bf16* ap = xs + lh * LDW;
    #pragma unroll
    for (int kk = 0; kk < 8; ++kk) {
      bf16x8 wq0 = *(const bf16x8*)(wlq + (0 * 8 + kk) * 512);
      bf16x8 wq1 = *(const bf16x8*)(wlq + (1 * 8 + kk) * 512);
      bf16x8 wk0 = *(const bf16x8*)(wlk + (0 * 8 + kk) * 512);
      bf16x8 wk1 = *(const bf16x8*)(wlk + (1 * 8 + kk) * 512);
      bf16x8 wv0 = *(const bf16x8*)(wlv + (0 * 8 + kk) * 512);
      bf16x8 wv1 = *(const bf16x8*)(wlv + (1 * 8 + kk) * 512);
      const int c = (kk * 32 + lq * 8) ^ xsw;
      bf16x8 a0 = *(const bf16x8*)(ap +  0 * LDW + c);
      bf16x8 a1 = *(const bf16x8*)(ap + 16 * LDW + c);
      MFMA(aq[0][0], a0, wq0); MFMA(aq[1][0], a1, wq0);
      MFMA(aq[0][1], a0, wq1); MFMA(aq[1][1], a1, wq1);
      MFMA(ak[0][0], a0, wk0); MFMA(ak[1][0], a1, wk0);
      MFMA(ak[0][1], a0, wk1); MFMA(ak[1][1], a1, wk1);
      MFMA(av[0][0], a0, wv0); MFMA(av[1][0], a1, wv0);
      MFMA(av[0][1], a0, wv1); MFMA(av[1][1], a1, wv1);
    }
    store_cd32(qs, aq, bq, n0, lh, lq);
    store_cd32(ksh, ak, bk, n0, lh, lq);
    store_cd32(vs, av, bv, n0, lh, lq);
  }
  __syncthreads();   // Q,K,V visible; xs reads complete

  // ---- fused softmax + y-mix: 16 threads/token, shfl-only, no PL/barrier ----
  {
    const int m   = tid >> 4;            // token 0..31
    const int sub = tid & 15;
    const int h   = sub & 3;             // head this thread scores
    const int kh  = sub >> 2;            // d-range quarter (16 elems)
    const int dof = kh * 16;
    const int msw = ((m >> 3) & 1) << 4;
    float d0 = 0.f, d1 = 0.f, d2 = 0.f, d3 = 0.f;
    #pragma unroll
    for (int i = 0; i < 2; ++i) {
      bf16x8 qv = *(const bf16x8*)&qs[m * LDW + ((h * 64 + dof + i * 8) ^ msw)];
      bf16x8 k0 = *(const bf16x8*)&ksh[m * LDW + ((  0 + dof + i * 8) ^ msw)];
      bf16x8 k1 = *(const bf16x8*)&ksh[m * LDW + (( 64 + dof + i * 8) ^ msw)];
      bf16x8 k2 = *(const bf16x8*)&ksh[m * LDW + ((128 + dof + i * 8) ^ msw)];
      bf16x8 k3 = *(const bf16x8*)&ksh[m * LDW + ((192 + dof + i * 8) ^ msw)];
      #pragma unroll
      for (int j = 0; j < 8; ++j) {
        float qf = (float)qv[j];
        d0 += qf * (float)k0[j];
        d1 += qf * (float)k1[j];
        d2 += qf * (float)k2[j];
        d3 += qf * (float)k3[j];
      }
    }
    // combine 4 d-quarters (lane bits 2-3 within the token's 16-lane group)
    d0 += __shfl_xor(d0, 4);  d0 += __shfl_xor(d0, 8);
    d1 += __shfl_xor(d1, 4);  d1 += __shfl_xor(d1, 8);
    d2 += __shfl_xor(d2, 4);  d2 += __shfl_xor(d2, 8);
    d3 += __shfl_xor(d3, 4);  d3 += __shfl_xor(d3, 8);
    d0 *= 0.125f; d1 *= 0.125f; d2 *= 0.125f; d3 *= 0.125f;  // 1/sqrt(64)
    float mx = fmaxf(fmaxf(d0, d1), fmaxf(d2, d3));
    float e0 = expf(d0 - mx), e1 = expf(d1 - mx), e2 = expf(d2 - mx), e3 = expf(d3 - mx);
    float inv = 1.0f / (e0 + e1 + e2 + e3);
    float pg0 = e0 * inv, pg1 = e1 * inv, pg2 = e2 * inv, pg3 = e3 * inv;

    // redistribute: ymix thread (hy = sub>>2) needs P[hy][0..3]; held by the
    // lane of the same token-group with sub' = hy (all kh copies identical).
    const int src = (lane & 48) | (sub >> 2);
    float p0 = __shfl(pg0, src);
    float p1 = __shfl(pg1, src);
    float p2 = __shfl(pg2, src);
    float p3 = __shfl(pg3, src);

    const int hy = sub >> 2;             // head whose output this thread writes
    const int c0 = (sub & 3) * 16;       // 16-col slice
    #pragma unroll
    for (int i = 0; i < 2; ++i) {
      int c = c0 + i * 8;
      bf16x8 v0 = *(const bf16x8*)&vs[m * LDW + ((  0 + c) ^ msw)];
      bf16x8 v1 = *(const bf16x8*)&vs[m * LDW + (( 64 + c) ^ msw)];
      bf16x8 v2 = *(const bf16x8*)&vs[m * LDW + ((128 + c) ^ msw)];
      bf16x8 v3 = *(const bf16x8*)&vs[m * LDW + ((192 + c) ^ msw)];
      bf16x8 yv;
      #pragma unroll
      for (int j = 0; j < 8; ++j) {
        float f = p0 * (float)v0[j] + p1 * (float)v1[j]
                + p2 * (float)v2[j] + p3 * (float)v3[j];
        yv[j] = (__bf16)f;
      }
      *(bf16x8*)&xs[m * LDW + ((hy * 64 + c) ^ msw)] = yv;   // Y over dead x
    }
  }
  __syncthreads();   // Y visible

  // ---- output GEMM: out = Y @ Wo^T + bo (A from LDS Y in xs) ----
  {
    f32x4 acc[2][2];
    ZERO_ACC22(acc);
    proj32(xs, wlo, lh, lq, acc);

    #pragma unroll
    for (int nf = 0; nf < 2; ++nf) {
      int col = n0 + nf * 16 + lh;
      float bb = bo[col];
      #pragma unroll
      for (int mf = 0; mf < 2; ++mf) {
        int rbase = tok0 + mf * 16 + lq * 4;
        #pragma unroll
        for (int j = 0; j < 4; ++j)
          out[(size_t)(rbase + j) * 256 + col] = acc[mf][nf][j] + bb;
      }
    }
  }
}

extern "C" void kernel_launch(void* const* d_in, const int* in_sizes, int n_in,
                              void* d_out, int out_size, void* d_ws, size_t ws_size,
                              hipStream_t stream) {
  const float* x  = (const float*)d_in[0];
  const float* Wq = (const float*)d_in[1];
  const float* bq = (const float*)d_in[2];
  const float* Wk = (const float*)d_in[3];
  const float* bk = (const float*)d_in[4];
  const float* Wv = (const float*)d_in[5];
  const float* bv = (const float*)d_in[6];
  const float* Wo = (const float*)d_in[7];
  const float* bo = (const float*)d_in[8];
  float* out = (float*)d_out;
  __bf16* Wpk = (__bf16*)d_ws;   // 512 frags x 1KB = 512 KB

  pack_wfrag<<<dim3(512), dim3(64), 0, stream>>>(Wq, Wk, Wv, Wo, Wpk);
  fused_attn<<<dim3(1024), dim3(512), 0, stream>>>(x, Wpk, bq, bk, bv, bo, out);
}